// Round 2
// baseline (349.516 us; speedup 1.0000x reference)
//
#include <hip/hip_runtime.h>

// R14: head-interleaved gather layouts. GEMM epilogue stores xwp[n][f][h] (P=6)
// and xwgp[n][f][g] (P=2) so gather lanes load their 6 (resp. 2) values as ONE
// aligned 12B (4B) vector load — 1 VMEM/edge/lane vs R12's 6, no LDS row
// redistribution. src/ex exchange uses R12's PROVEN barrier discipline
// (mc_sh + __syncthreads per chunk; R13's barrier-free wave-sync LDS was the
// correctness failure). ex read as float2 x3. Parallel k_scan + fused dual-output
// GEMM (GEMM2+GEMM3 share A=h) kept from R13. 14 launches total.

#define NN 20000
#define EE 320000
#define GATD 384
#define NH 6
#define OUTD 64
#define ODIM 576

typedef __bf16 bf16_8 __attribute__((ext_vector_type(8)));
typedef float f32_4 __attribute__((ext_vector_type(4)));

struct u96 { unsigned x, y, z; };  // 12B, align 4 -> dwordx3

__device__ __forceinline__ float lrelu(float x, float s) { return x > 0.f ? x : s * x; }
__device__ __forceinline__ float bflo(unsigned p) { return __uint_as_float(p << 16); }
__device__ __forceinline__ float bfhi(unsigned p) { return __uint_as_float(p & 0xffff0000u); }

__device__ __forceinline__ float loadf(const void* p, size_t i, int f32) {
  return f32 ? ((const float*)p)[i] : (float)((const __bf16*)p)[i];
}

// ---------- fused dtype probes ----------
struct ProbeArgs {
  const void* ptr[15];
  int cnt[15];
  int flagidx[15];
  const int* ei;
};
__global__ void k_probe_all(ProbeArgs a, int* __restrict__ flags) {
  __shared__ int cnt;
  if (threadIdx.x == 0) cnt = 0;
  __syncthreads();
  int b = blockIdx.x;
  if (b < 15) {
    const unsigned short* u = (const unsigned short*)a.ptr[b];
    int m = a.cnt[b] < 2048 ? a.cnt[b] : 2048;
    int c = 0;
    for (int i = threadIdx.x; i < m; i += 256) {
      float v = __uint_as_float(((unsigned int)u[i]) << 16);
      if (!(fabsf(v) < 1e4f)) c++;
    }
    if (c) atomicAdd(&cnt, c);
    __syncthreads();
    if (threadIdx.x == 0) flags[a.flagidx[b]] = (cnt > m / 16) ? 1 : 0;
  } else {
    int c = 0;
    for (int i = threadIdx.x; i < 1024; i += 256)
      if (a.ei[2 * i + 1] != 0) c++;
    if (c) atomicAdd(&cnt, c);
    __syncthreads();
    if (threadIdx.x == 0) flags[16] = (cnt <= 2) ? 1 : 0;
  }
}

// ---------- fused small-tensor conversions (7 segments) ----------
struct CvtSeg { const void* in; __bf16* out; int n; int flagidx; int blk0; };
struct CvtArgs { CvtSeg s[7]; };
__global__ void k_cvt_all(CvtArgs a, const int* __restrict__ flags) {
  int b = blockIdx.x;
  int k = 0;
  while (k + 1 < 7 && a.s[k + 1].blk0 <= b) k++;
  const CvtSeg sg = a.s[k];
  int i = (b - sg.blk0) * 256 + threadIdx.x;
  if (i >= sg.n) return;
  sg.out[i] = flags[sg.flagidx] ? (__bf16)((const float*)sg.in)[i] : ((const __bf16*)sg.in)[i];
}

// ---------- fused cvt+transpose for weight matrices: in [R][C] (fp32|bf16) -> out [C][R] bf16 ----------
struct TSeg { const void* in; __bf16* out; int R; int C; int flagidx; int blk0; };
struct TArgs { TSeg s[6]; };
__global__ void k_cvt_t_all(TArgs a, const int* __restrict__ flags) {
  __shared__ float t[32][33];
  int b = blockIdx.x;
  int k = 0;
  while (k + 1 < 6 && a.s[k + 1].blk0 <= b) k++;
  const TSeg sg = a.s[k];
  int f32 = flags[sg.flagidx];
  int tpx = (sg.C + 31) >> 5;
  int lt = b - sg.blk0;
  int c0 = (lt % tpx) * 32, r0 = (lt / tpx) * 32;
  int tid = threadIdx.x;
  for (int idx = tid; idx < 1024; idx += 256) {
    int r = idx >> 5, c = idx & 31;
    if (r0 + r < sg.R && c0 + c < sg.C)
      t[r][c] = loadf(sg.in, (size_t)(r0 + r) * sg.C + (c0 + c), f32);
  }
  __syncthreads();
  for (int idx = tid; idx < 1024; idx += 256) {
    int r = idx >> 5, c = idx & 31;
    if (c0 + r < sg.C && r0 + c < sg.R)
      sg.out[(size_t)(c0 + r) * sg.R + (r0 + c)] = (__bf16)t[c][r];
  }
}

// ---------- CSR build ----------
__global__ void k_count(const int* __restrict__ ei, const void* __restrict__ ew,
                        const int* __restrict__ flags,
                        int* __restrict__ deg, float* __restrict__ wdeg) {
  int e = blockIdx.x * 256 + threadIdx.x;
  if (e >= EE) return;
  int sh = flags[16];
  int d = ei[(size_t)(EE + e) << sh];
  atomicAdd(&deg[d], 1);
  atomicAdd(&wdeg[d], loadf(ew, e, flags[2]));
}

// parallel scan: per-thread run sums, wave shuffle-scan, cross-wave via wsum
__global__ __launch_bounds__(256) void k_scan(const int* __restrict__ deg, int* __restrict__ rowstart) {
  __shared__ int wsum[4];
  int t = threadIdx.x;
  const int per = (NN + 255) / 256;
  int lo = t * per; if (lo > NN) lo = NN;
  int hi = lo + per; if (hi > NN) hi = NN;
  int s = 0;
  for (int i = lo; i < hi; i++) s += deg[i];
  int lane = t & 63, wv = t >> 6;
  int run = s;
  for (int off = 1; off < 64; off <<= 1) {
    int u = __shfl_up(run, off);
    if (lane >= off) run += u;
  }
  if (lane == 63) wsum[wv] = run;
  __syncthreads();
  int wbase = 0;
#pragma unroll
  for (int w = 0; w < 4; w++) { int v = wsum[w]; if (w < wv) wbase += v; }
  int a = wbase + run - s;  // exclusive prefix for this thread's run
  for (int i = lo; i < hi; i++) { rowstart[i] = a; a += deg[i]; }
  if (t == 255) rowstart[NN] = a;
}

__global__ void k_fill(const int* __restrict__ ei, const void* __restrict__ ew,
                       const int* __restrict__ flags, const int* __restrict__ rowstart,
                       int* __restrict__ cursor,
                       int* __restrict__ csr_src, float* __restrict__ csr_w) {
  int e = blockIdx.x * 256 + threadIdx.x;
  if (e >= EE) return;
  int sh = flags[16];
  int d = ei[(size_t)(EE + e) << sh];
  int s = ei[(size_t)e << sh];
  int pos = rowstart[d] + atomicAdd(&cursor[d], 1);
  csr_src[pos] = s;
  csr_w[pos] = loadf(ew, e, flags[2]);
}

__global__ void k_dinv(const float* __restrict__ wdeg, float* __restrict__ dg, float* __restrict__ da) {
  int i = blockIdx.x * 256 + threadIdx.x;
  if (i >= NN) return;
  float w = wdeg[i];
  dg[i] = rsqrtf(w + 1.0f);
  da[i] = w > 0.f ? rsqrtf(w) : 0.f;
}

// ---------- MFMA GEMM: C[M][N] = A[M][K] * Bt[N][K]^T (+bias), bf16 out ----------
// Dual-output epilogue (col0 < n1 -> C1 else C2, col rebased). P>1 stores
// head-interleaved: column (f*64-block h, offset f) lands at f*P + h.
template<bool HAS_BIAS>
__global__ __launch_bounds__(256) void gemm64(const void* __restrict__ A,
    const int* __restrict__ aflag, const __bf16* __restrict__ Bt,
    const __bf16* __restrict__ bias,
    __bf16* __restrict__ C1, int n1, int ldc1, int P1,
    __bf16* __restrict__ C2, int ldc2, int P2,
    int M, int K) {
  __shared__ __bf16 Al[64][40];
  __shared__ __bf16 Bl[64][40];
  int a32 = *aflag;
  int tid = threadIdx.x;
  int w = tid >> 6, lane = tid & 63;
  int quad = lane >> 4, r = lane & 15;
  int row0 = blockIdx.x * 64, col0 = blockIdx.y * 64;
  f32_4 acc[4] = {};
  int srow = tid >> 2;
  int koff = (tid & 3) * 8;
  for (int kt = 0; kt < K; kt += 32) {
    int arow = row0 + srow;
    if (a32) {
      float4 a0 = {0.f, 0.f, 0.f, 0.f}, a1 = {0.f, 0.f, 0.f, 0.f};
      if (arow < M) {
        const float* ap = (const float*)A + (size_t)arow * K + kt + koff;
        a0 = *(const float4*)ap;
        a1 = *(const float4*)(ap + 4);
      }
      bf16_8 t;
      t[0] = (__bf16)a0.x; t[1] = (__bf16)a0.y; t[2] = (__bf16)a0.z; t[3] = (__bf16)a0.w;
      t[4] = (__bf16)a1.x; t[5] = (__bf16)a1.y; t[6] = (__bf16)a1.z; t[7] = (__bf16)a1.w;
      *(bf16_8*)(&Al[srow][koff]) = t;
    } else {
      float4 av = {0.f, 0.f, 0.f, 0.f};
      if (arow < M) av = *(const float4*)((const __bf16*)A + (size_t)arow * K + kt + koff);
      *(float4*)(&Al[srow][koff]) = av;
    }
    float4 bv = *(const float4*)(Bt + (size_t)(col0 + srow) * K + kt + koff);
    *(float4*)(&Bl[srow][koff]) = bv;
    __syncthreads();
    bf16_8 bfrag = *(const bf16_8*)(&Bl[w * 16 + r][quad * 8]);
#pragma unroll
    for (int mt = 0; mt < 4; mt++) {
      bf16_8 afrag = *(const bf16_8*)(&Al[mt * 16 + r][quad * 8]);
      acc[mt] = __builtin_amdgcn_mfma_f32_16x16x32_bf16(afrag, bfrag, acc[mt], 0, 0, 0);
    }
    __syncthreads();
  }
  int ccg = col0 + w * 16 + r;  // global output column
  __bf16* Cp; int ldc; int ccol; int P;
  if (col0 < n1) { Cp = C1; ldc = ldc1; ccol = ccg; P = P1; }
  else           { Cp = C2; ldc = ldc2; ccol = ccg - n1; P = P2; }
  int cc = (P > 1) ? ((ccol & 63) * P + (ccol >> 6)) : ccol;
  float bv = HAS_BIAS ? (float)bias[ccg] : 0.0f;
#pragma unroll
  for (int mt = 0; mt < 4; mt++) {
#pragma unroll
    for (int rr = 0; rr < 4; rr++) {
      int crow = row0 + mt * 16 + quad * 4 + rr;
      if (crow < M) Cp[(size_t)crow * ldc + cc] = (__bf16)(acc[mt][rr] + bv);
    }
  }
}

// ---------- attention logits: wave per node, head-interleaved layout ----------
__global__ void k_alar_w(const __bf16* __restrict__ xwp, const __bf16* __restrict__ as_,
                         const __bf16* __restrict__ ad_,
                         float* __restrict__ al, float* __restrict__ ar) {
  int i = blockIdx.x * 4 + (threadIdx.x >> 6);
  int lane = threadIdx.x & 63;
  if (i >= NN) return;
  u96 u = *(const u96*)(xwp + (size_t)i * GATD + lane * 6);
  float v[NH] = {bflo(u.x), bfhi(u.x), bflo(u.y), bfhi(u.y), bflo(u.z), bfhi(u.z)};
#pragma unroll
  for (int h = 0; h < NH; h++) {
    float s1 = v[h] * (float)as_[h * OUTD + lane];
    float s2 = v[h] * (float)ad_[h * OUTD + lane];
    for (int off = 32; off; off >>= 1) { s1 += __shfl_xor(s1, off); s2 += __shfl_xor(s2, off); }
    if (lane == 0) { al[i * NH + h] = s1; ar[i * NH + h] = s2; }
  }
}

// ---------- GAT: wave per node; per-lane dwordx3 row gather (xwp[n][f][h]) ----------
// R12-proven barrier discipline: src/ex written before __syncthreads, read after.
__global__ __launch_bounds__(256) void k_gat2(const __bf16* __restrict__ xwp,
    const float* __restrict__ al, const float* __restrict__ ar,
    const int* __restrict__ rowstart, const int* __restrict__ csr_src,
    const __bf16* __restrict__ bgat,
    __bf16* __restrict__ h1b, float* __restrict__ out) {
  int wv = threadIdx.x >> 6, lane = threadIdx.x & 63;
  int i = blockIdx.x * 4 + wv;           // NN % 4 == 0
  __shared__ int   src_sh[4][64];
  __shared__ __attribute__((aligned(16))) float ex_sh[4][64][NH];
  __shared__ int   mc_sh[4];
  int e0 = rowstart[i], e1 = rowstart[i + 1];
  if (lane == 0) mc_sh[wv] = (e1 - e0 + 63) >> 6;
  float arv[NH], exs[NH], acc[NH], denp[NH];
#pragma unroll
  for (int h = 0; h < NH; h++) arv[h] = ar[i * NH + h];
  u96 us = *(const u96*)(xwp + (size_t)i * GATD + lane * 6);
  float sv[NH] = {bflo(us.x), bfhi(us.x), bflo(us.y), bfhi(us.y), bflo(us.z), bfhi(us.z)};
#pragma unroll
  for (int h = 0; h < NH; h++) {
    float e = lrelu(al[i * NH + h] + arv[h], 0.2f);
    exs[h] = __expf(e);                  // self-loop weight
    acc[h] = exs[h] * sv[h];
    denp[h] = 0.f;
  }
  __syncthreads();
  int mch = max(max(mc_sh[0], mc_sh[1]), max(mc_sh[2], mc_sh[3]));
  for (int c = 0; c < mch; c++) {
    if (c) __syncthreads();
    int base = e0 + c * 64;
    int cnt = e1 - base; cnt = cnt < 0 ? 0 : (cnt > 64 ? 64 : cnt);
    if (lane < cnt) {
      int s = csr_src[base + lane];
      src_sh[wv][lane] = s;
#pragma unroll
      for (int h = 0; h < NH; h++) {
        float ex = __expf(lrelu(al[s * NH + h] + arv[h], 0.2f));
        ex_sh[wv][lane][h] = ex;
        denp[h] += ex;
      }
    }
    __syncthreads();
    int j = 0;
    for (; j + 2 <= cnt; j += 2) {
      int2 ss = *(const int2*)&src_sh[wv][j];
      u96 u0 = *(const u96*)(xwp + (size_t)ss.x * GATD + lane * 6);
      u96 u1 = *(const u96*)(xwp + (size_t)ss.y * GATD + lane * 6);
      const float2* ep0 = (const float2*)ex_sh[wv][j];
      const float2* ep1 = (const float2*)ex_sh[wv][j + 1];
      float2 ea0 = ep0[0], eb0 = ep0[1], ec0 = ep0[2];
      float2 ea1 = ep1[0], eb1 = ep1[1], ec1 = ep1[2];
      acc[0] += ea0.x * bflo(u0.x) + ea1.x * bflo(u1.x);
      acc[1] += ea0.y * bfhi(u0.x) + ea1.y * bfhi(u1.x);
      acc[2] += eb0.x * bflo(u0.y) + eb1.x * bflo(u1.y);
      acc[3] += eb0.y * bfhi(u0.y) + eb1.y * bfhi(u1.y);
      acc[4] += ec0.x * bflo(u0.z) + ec1.x * bflo(u1.z);
      acc[5] += ec0.y * bfhi(u0.z) + ec1.y * bfhi(u1.z);
    }
    if (j < cnt) {
      int s0 = src_sh[wv][j];
      u96 u0 = *(const u96*)(xwp + (size_t)s0 * GATD + lane * 6);
      const float2* ep0 = (const float2*)ex_sh[wv][j];
      float2 ea0 = ep0[0], eb0 = ep0[1], ec0 = ep0[2];
      acc[0] += ea0.x * bflo(u0.x);
      acc[1] += ea0.y * bfhi(u0.x);
      acc[2] += eb0.x * bflo(u0.y);
      acc[3] += eb0.y * bfhi(u0.y);
      acc[4] += ec0.x * bflo(u0.z);
      acc[5] += ec0.y * bfhi(u0.z);
    }
  }
#pragma unroll
  for (int h = 0; h < NH; h++) {
    float d = denp[h];
    for (int off = 32; off; off >>= 1) d += __shfl_xor(d, off);
    d += exs[h];
    float v = acc[h] / d + (float)bgat[h * OUTD + lane];
    v = lrelu(v, 0.01f);
    h1b[(size_t)i * GATD + h * OUTD + lane] = (__bf16)v;   // standard layout (GEMM-3 A)
    out[(size_t)i * ODIM + h * OUTD + lane] = tanhf(v);
  }
}

// ---------- fused GCN0+GCN1+ARMA: wave per node; xwgp[n][f][g] 4B gather ----------
__global__ __launch_bounds__(256) void k_gcnarma2(const __bf16* __restrict__ xwgp,
    const __bf16* __restrict__ trb, const int* __restrict__ rowstart,
    const int* __restrict__ csr_src, const float* __restrict__ csr_w,
    const float* __restrict__ dgcn, const float* __restrict__ darma,
    const __bf16* __restrict__ b0, const __bf16* __restrict__ b1,
    const __bf16* __restrict__ ba, float* __restrict__ out) {
  int wv = threadIdx.x >> 6, lane = threadIdx.x & 63;
  int i = blockIdx.x * 4 + wv;
  __shared__ int   src_sh[4][64];
  __shared__ __attribute__((aligned(16))) float wg_sh[4][64], wa_sh[4][64];
  __shared__ int   mc_sh[4];
  int e0 = rowstart[i], e1 = rowstart[i + 1];
  if (lane == 0) mc_sh[wv] = (e1 - e0 + 63) >> 6;
  __syncthreads();
  int mch = max(max(mc_sh[0], mc_sh[1]), max(mc_sh[2], mc_sh[3]));
  float g0 = 0.f, g1 = 0.f, aa = 0.f;
  for (int c = 0; c < mch; c++) {
    if (c) __syncthreads();
    int base = e0 + c * 64;
    int cnt = e1 - base; cnt = cnt < 0 ? 0 : (cnt > 64 ? 64 : cnt);
    if (lane < cnt) {
      int eidx = base + lane;
      int s = csr_src[eidx];
      float wvv = csr_w[eidx];
      src_sh[wv][lane] = s;
      wg_sh[wv][lane] = dgcn[s] * wvv;
      wa_sh[wv][lane] = darma[s] * wvv;
    }
    __syncthreads();
    int j = 0;
    for (; j + 2 <= cnt; j += 2) {
      int2 ss = *(const int2*)&src_sh[wv][j];
      float2 wg = *(const float2*)&wg_sh[wv][j];
      float2 wa = *(const float2*)&wa_sh[wv][j];
      unsigned x0 = *(const unsigned*)(xwgp + (size_t)ss.x * 128 + lane * 2);
      unsigned x1 = *(const unsigned*)(xwgp + (size_t)ss.y * 128 + lane * 2);
      float t0 = (float)trb[(size_t)ss.x * 128 + lane];
      float t1 = (float)trb[(size_t)ss.y * 128 + lane];
      g0 += wg.x * bflo(x0) + wg.y * bflo(x1);
      g1 += wg.x * bfhi(x0) + wg.y * bfhi(x1);
      aa += wa.x * t0 + wa.y * t1;
    }
    if (j < cnt) {
      int s0 = src_sh[wv][j];
      float wgx = wg_sh[wv][j], wax = wa_sh[wv][j];
      unsigned x0 = *(const unsigned*)(xwgp + (size_t)s0 * 128 + lane * 2);
      float t0 = (float)trb[(size_t)s0 * 128 + lane];
      g0 += wgx * bflo(x0);
      g1 += wgx * bfhi(x0);
      aa += wax * t0;
    }
  }
  float di = dgcn[i];
  unsigned xs = *(const unsigned*)(xwgp + (size_t)i * 128 + lane * 2);
  float v0 = lrelu(di * g0 + di * di * bflo(xs) + (float)b0[lane], 0.01f);
  float v1 = lrelu(di * g1 + di * di * bfhi(xs) + (float)b1[lane], 0.01f);
  out[(size_t)i * ODIM + 384 + lane] = tanhf(v0);
  out[(size_t)i * ODIM + 448 + lane] = tanhf(v1);
  float va = darma[i] * aa + (float)trb[(size_t)i * 128 + 64 + lane] + (float)ba[lane];
  va = fmaxf(va, 0.f);
  out[(size_t)i * ODIM + 512 + lane] = tanhf(va);
}

extern "C" void kernel_launch(void* const* d_in, const int* in_sizes, int n_in,
                              void* d_out, int out_size, void* d_ws, size_t ws_size,
                              hipStream_t stream) {
  const int* ei = (const int*)d_in[1];
  float* out = (float*)d_out;

  char* ws = (char*)d_ws;
  size_t off = 0;
  auto alloc = [&](size_t bytes) -> void* {
    void* p = ws + off;
    off += (bytes + 255) & ~(size_t)255;
    return p;
  };
  int*    flags    = (int*)alloc(32 * 4);
  int*    deg      = (int*)alloc((size_t)3 * NN * 4);
  int*    cursor   = deg + NN;
  float*  wdeg     = (float*)(deg + 2 * NN);
  int*    rowstart = (int*)alloc((size_t)(NN + 1) * 4);
  int*    csr_src  = (int*)alloc((size_t)EE * 4);
  float*  csr_w    = (float*)alloc((size_t)EE * 4);
  float*  dgcn     = (float*)alloc((size_t)NN * 4);
  float*  darma    = (float*)alloc((size_t)NN * 4);
  float*  al       = (float*)alloc((size_t)NN * NH * 4);
  float*  ar       = (float*)alloc((size_t)NN * NH * 4);
  __bf16* bpb   = (__bf16*)alloc(256 * 2);
  __bf16* asb   = (__bf16*)alloc(384 * 2);
  __bf16* adb   = (__bf16*)alloc(384 * 2);
  __bf16* bgatb = (__bf16*)alloc(384 * 2);
  __bf16* bg0b  = (__bf16*)alloc(64 * 2);
  __bf16* bg1b  = (__bf16*)alloc(64 * 2);
  __bf16* bab   = (__bf16*)alloc(64 * 2);
  __bf16* Wp_t    = (__bf16*)alloc(256 * 256 * 2);
  // Wgat_t and Wg01_t in one contiguous buffer -> single fused GEMM (N=512)
  __bf16* Wcat_t  = (__bf16*)alloc((size_t)(384 + 128) * 256 * 2);
  __bf16* Wgat_t  = Wcat_t;
  __bf16* Wg01_t  = Wcat_t + (size_t)384 * 256;
  __bf16* Warma_t = (__bf16*)alloc(128 * 384 * 2);
  char* regA = (char*)alloc((size_t)NN * GATD * 2);
  __bf16* h   = (__bf16*)regA;   // dead after fused gemm
  __bf16* h1b = (__bf16*)regA;
  char* regB = (char*)alloc((size_t)NN * GATD * 2);
  __bf16* xwp = (__bf16*)regB;   // head-interleaved [n][f][h]; dead after k_gat2
  __bf16* trb = (__bf16*)regB;
  __bf16* xwgp = (__bf16*)alloc((size_t)NN * 128 * 2);  // [n][f][g]
  (void)ws_size; (void)in_sizes; (void)n_in; (void)out_size;

  hipMemsetAsync(ws, 0, 256 + (size_t)3 * NN * 4, stream);

  dim3 tb(256);
  // fused probes
  ProbeArgs pa;
  const int pidx[15] = {0, 2, 3, 4, 5, 6, 7, 8, 9, 10, 11, 12, 13, 14, 15};
  const int pcnt[15] = {NN * 256, EE, 256 * 256, 256, 256 * 384, NH * OUTD, NH * OUTD,
                        NH * OUTD, 256 * 64, 64, 256 * 64, 64, GATD * OUTD, GATD * OUTD, 64};
  for (int k = 0; k < 15; k++) { pa.ptr[k] = d_in[pidx[k]]; pa.cnt[k] = pcnt[k]; pa.flagidx[k] = pidx[k]; }
  pa.ei = ei;
  k_probe_all<<<dim3(16), tb, 0, stream>>>(pa, flags);

  // fused small-tensor conversions (biases + attention vectors)
  CvtArgs ca;
  {
    struct { int idx; __bf16* out; int n; } cv[7] = {
      {4, bpb, 256}, {6, asb, 384}, {7, adb, 384}, {8, bgatb, 384},
      {10, bg0b, 64}, {12, bg1b, 64}, {15, bab, 64},
    };
    int blk = 0;
    for (int k = 0; k < 7; k++) {
      ca.s[k].in = d_in[cv[k].idx]; ca.s[k].out = cv[k].out; ca.s[k].n = cv[k].n;
      ca.s[k].flagidx = cv[k].idx; ca.s[k].blk0 = blk;
      blk += (cv[k].n + 255) / 256;
    }
    k_cvt_all<<<dim3(blk), tb, 0, stream>>>(ca, flags);
  }

  // fused cvt+transpose for the 6 weight matrices (raw d_in -> Bt bf16)
  TArgs ta;
  {
    struct { int idx; __bf16* out; int R; int C; } tv[6] = {
      {3,  Wp_t,             256, 256},
      {5,  Wgat_t,           256, 384},
      {9,  Wg01_t,           256, 64},
      {11, Wg01_t + 64 * 256, 256, 64},
      {13, Warma_t,          384, 64},
      {14, Warma_t + 64 * 384, 384, 64},
    };
    int blk = 0;
    for (int k = 0; k < 6; k++) {
      ta.s[k].in = d_in[tv[k].idx]; ta.s[k].out = tv[k].out;
      ta.s[k].R = tv[k].R; ta.s[k].C = tv[k].C;
      ta.s[k].flagidx = tv[k].idx; ta.s[k].blk0 = blk;
      blk += ((tv[k].R + 31) / 32) * ((tv[k].C + 31) / 32);
    }
    k_cvt_t_all<<<dim3(blk), tb, 0, stream>>>(ta, flags);
  }

  // CSR by dst + degree norms
  k_count<<<dim3((EE + 255) / 256), tb, 0, stream>>>(ei, d_in[2], flags, deg, wdeg);
  k_scan<<<dim3(1), tb, 0, stream>>>(deg, rowstart);
  k_fill<<<dim3((EE + 255) / 256), tb, 0, stream>>>(ei, d_in[2], flags, rowstart, cursor, csr_src, csr_w);
  k_dinv<<<dim3((NN + 255) / 256), tb, 0, stream>>>(wdeg, dgcn, darma);

  const int MB64 = (NN + 63) / 64;  // 313
  // h = x @ Wp + bp (standard layout)
  gemm64<true ><<<dim3(MB64, 4), tb, 0, stream>>>(d_in[0], &flags[0], Wp_t, bpb,
                                                  h, 256, 256, 1, nullptr, 0, 1, NN, 256);
  // fused: xwp = perm6(h @ Wgat) (cols 0..383), xwgp = perm2(h @ Wgcn01) (cols 384..511)
  gemm64<false><<<dim3(MB64, 8), tb, 0, stream>>>(h, &flags[30], Wcat_t, nullptr,
                                                  xwp, 384, 384, 6, xwgp, 128, 2, NN, 256);
  k_alar_w<<<dim3(NN / 4), tb, 0, stream>>>(xwp, asb, adb, al, ar);
  // h dead; h1b overwrites region A
  k_gat2<<<dim3(NN / 4), tb, 0, stream>>>(xwp, al, ar, rowstart, csr_src, bgatb, h1b, out);
  // xwp dead; trb overwrites region B (identity layout)
  gemm64<false><<<dim3(MB64, 2), tb, 0, stream>>>(h1b, &flags[30], Warma_t, nullptr,
                                                  trb, 128, 128, 1, nullptr, 0, 1, NN, 384);
  k_gcnarma2<<<dim3(NN / 4), tb, 0, stream>>>(xwgp, trb, rowstart, csr_src, csr_w,
                                              dgcn, darma, bg0b, bg1b, bab, out);
}

// Round 3
// 349.244 us; speedup vs baseline: 1.0008x; 1.0008x over previous
//
#include <hip/hip_runtime.h>

// R15: deep-MLP gather. R14's head-interleaved layout made the per-edge load a
// single dwordx3 but cut loads-in-flight 12->2 (latency-bound regression).
// R15 unrolls the gather 8 edges/iter: 8 independent row loads issued before
// any consumption. Chunks padded to a multiple of 8 with (src=i, ex/w=0) edges
// (written pre-barrier by all lanes — proven discipline) so no serial tail.
// Same in k_gcnarma2 (8 dword + 8 ushort in flight). Rest identical to R14.

#define NN 20000
#define EE 320000
#define GATD 384
#define NH 6
#define OUTD 64
#define ODIM 576

typedef __bf16 bf16_8 __attribute__((ext_vector_type(8)));
typedef float f32_4 __attribute__((ext_vector_type(4)));

struct u96 { unsigned x, y, z; };  // 12B, align 4 -> dwordx3

__device__ __forceinline__ float lrelu(float x, float s) { return x > 0.f ? x : s * x; }
__device__ __forceinline__ float bflo(unsigned p) { return __uint_as_float(p << 16); }
__device__ __forceinline__ float bfhi(unsigned p) { return __uint_as_float(p & 0xffff0000u); }

__device__ __forceinline__ float loadf(const void* p, size_t i, int f32) {
  return f32 ? ((const float*)p)[i] : (float)((const __bf16*)p)[i];
}

// ---------- fused dtype probes ----------
struct ProbeArgs {
  const void* ptr[15];
  int cnt[15];
  int flagidx[15];
  const int* ei;
};
__global__ void k_probe_all(ProbeArgs a, int* __restrict__ flags) {
  __shared__ int cnt;
  if (threadIdx.x == 0) cnt = 0;
  __syncthreads();
  int b = blockIdx.x;
  if (b < 15) {
    const unsigned short* u = (const unsigned short*)a.ptr[b];
    int m = a.cnt[b] < 2048 ? a.cnt[b] : 2048;
    int c = 0;
    for (int i = threadIdx.x; i < m; i += 256) {
      float v = __uint_as_float(((unsigned int)u[i]) << 16);
      if (!(fabsf(v) < 1e4f)) c++;
    }
    if (c) atomicAdd(&cnt, c);
    __syncthreads();
    if (threadIdx.x == 0) flags[a.flagidx[b]] = (cnt > m / 16) ? 1 : 0;
  } else {
    int c = 0;
    for (int i = threadIdx.x; i < 1024; i += 256)
      if (a.ei[2 * i + 1] != 0) c++;
    if (c) atomicAdd(&cnt, c);
    __syncthreads();
    if (threadIdx.x == 0) flags[16] = (cnt <= 2) ? 1 : 0;
  }
}

// ---------- fused small-tensor conversions (7 segments) ----------
struct CvtSeg { const void* in; __bf16* out; int n; int flagidx; int blk0; };
struct CvtArgs { CvtSeg s[7]; };
__global__ void k_cvt_all(CvtArgs a, const int* __restrict__ flags) {
  int b = blockIdx.x;
  int k = 0;
  while (k + 1 < 7 && a.s[k + 1].blk0 <= b) k++;
  const CvtSeg sg = a.s[k];
  int i = (b - sg.blk0) * 256 + threadIdx.x;
  if (i >= sg.n) return;
  sg.out[i] = flags[sg.flagidx] ? (__bf16)((const float*)sg.in)[i] : ((const __bf16*)sg.in)[i];
}

// ---------- fused cvt+transpose for weight matrices: in [R][C] (fp32|bf16) -> out [C][R] bf16 ----------
struct TSeg { const void* in; __bf16* out; int R; int C; int flagidx; int blk0; };
struct TArgs { TSeg s[6]; };
__global__ void k_cvt_t_all(TArgs a, const int* __restrict__ flags) {
  __shared__ float t[32][33];
  int b = blockIdx.x;
  int k = 0;
  while (k + 1 < 6 && a.s[k + 1].blk0 <= b) k++;
  const TSeg sg = a.s[k];
  int f32 = flags[sg.flagidx];
  int tpx = (sg.C + 31) >> 5;
  int lt = b - sg.blk0;
  int c0 = (lt % tpx) * 32, r0 = (lt / tpx) * 32;
  int tid = threadIdx.x;
  for (int idx = tid; idx < 1024; idx += 256) {
    int r = idx >> 5, c = idx & 31;
    if (r0 + r < sg.R && c0 + c < sg.C)
      t[r][c] = loadf(sg.in, (size_t)(r0 + r) * sg.C + (c0 + c), f32);
  }
  __syncthreads();
  for (int idx = tid; idx < 1024; idx += 256) {
    int r = idx >> 5, c = idx & 31;
    if (c0 + r < sg.C && r0 + c < sg.R)
      sg.out[(size_t)(c0 + r) * sg.R + (r0 + c)] = (__bf16)t[c][r];
  }
}

// ---------- CSR build ----------
__global__ void k_count(const int* __restrict__ ei, const void* __restrict__ ew,
                        const int* __restrict__ flags,
                        int* __restrict__ deg, float* __restrict__ wdeg) {
  int e = blockIdx.x * 256 + threadIdx.x;
  if (e >= EE) return;
  int sh = flags[16];
  int d = ei[(size_t)(EE + e) << sh];
  atomicAdd(&deg[d], 1);
  atomicAdd(&wdeg[d], loadf(ew, e, flags[2]));
}

// parallel scan: per-thread run sums, wave shuffle-scan, cross-wave via wsum
__global__ __launch_bounds__(256) void k_scan(const int* __restrict__ deg, int* __restrict__ rowstart) {
  __shared__ int wsum[4];
  int t = threadIdx.x;
  const int per = (NN + 255) / 256;
  int lo = t * per; if (lo > NN) lo = NN;
  int hi = lo + per; if (hi > NN) hi = NN;
  int s = 0;
  for (int i = lo; i < hi; i++) s += deg[i];
  int lane = t & 63, wv = t >> 6;
  int run = s;
  for (int off = 1; off < 64; off <<= 1) {
    int u = __shfl_up(run, off);
    if (lane >= off) run += u;
  }
  if (lane == 63) wsum[wv] = run;
  __syncthreads();
  int wbase = 0;
#pragma unroll
  for (int w = 0; w < 4; w++) { int v = wsum[w]; if (w < wv) wbase += v; }
  int a = wbase + run - s;  // exclusive prefix for this thread's run
  for (int i = lo; i < hi; i++) { rowstart[i] = a; a += deg[i]; }
  if (t == 255) rowstart[NN] = a;
}

__global__ void k_fill(const int* __restrict__ ei, const void* __restrict__ ew,
                       const int* __restrict__ flags, const int* __restrict__ rowstart,
                       int* __restrict__ cursor,
                       int* __restrict__ csr_src, float* __restrict__ csr_w) {
  int e = blockIdx.x * 256 + threadIdx.x;
  if (e >= EE) return;
  int sh = flags[16];
  int d = ei[(size_t)(EE + e) << sh];
  int s = ei[(size_t)e << sh];
  int pos = rowstart[d] + atomicAdd(&cursor[d], 1);
  csr_src[pos] = s;
  csr_w[pos] = loadf(ew, e, flags[2]);
}

__global__ void k_dinv(const float* __restrict__ wdeg, float* __restrict__ dg, float* __restrict__ da) {
  int i = blockIdx.x * 256 + threadIdx.x;
  if (i >= NN) return;
  float w = wdeg[i];
  dg[i] = rsqrtf(w + 1.0f);
  da[i] = w > 0.f ? rsqrtf(w) : 0.f;
}

// ---------- MFMA GEMM: C[M][N] = A[M][K] * Bt[N][K]^T (+bias), bf16 out ----------
// Dual-output epilogue (col0 < n1 -> C1 else C2, col rebased). P>1 stores
// head-interleaved: column (f*64-block h, offset f) lands at f*P + h.
template<bool HAS_BIAS>
__global__ __launch_bounds__(256) void gemm64(const void* __restrict__ A,
    const int* __restrict__ aflag, const __bf16* __restrict__ Bt,
    const __bf16* __restrict__ bias,
    __bf16* __restrict__ C1, int n1, int ldc1, int P1,
    __bf16* __restrict__ C2, int ldc2, int P2,
    int M, int K) {
  __shared__ __bf16 Al[64][40];
  __shared__ __bf16 Bl[64][40];
  int a32 = *aflag;
  int tid = threadIdx.x;
  int w = tid >> 6, lane = tid & 63;
  int quad = lane >> 4, r = lane & 15;
  int row0 = blockIdx.x * 64, col0 = blockIdx.y * 64;
  f32_4 acc[4] = {};
  int srow = tid >> 2;
  int koff = (tid & 3) * 8;
  for (int kt = 0; kt < K; kt += 32) {
    int arow = row0 + srow;
    if (a32) {
      float4 a0 = {0.f, 0.f, 0.f, 0.f}, a1 = {0.f, 0.f, 0.f, 0.f};
      if (arow < M) {
        const float* ap = (const float*)A + (size_t)arow * K + kt + koff;
        a0 = *(const float4*)ap;
        a1 = *(const float4*)(ap + 4);
      }
      bf16_8 t;
      t[0] = (__bf16)a0.x; t[1] = (__bf16)a0.y; t[2] = (__bf16)a0.z; t[3] = (__bf16)a0.w;
      t[4] = (__bf16)a1.x; t[5] = (__bf16)a1.y; t[6] = (__bf16)a1.z; t[7] = (__bf16)a1.w;
      *(bf16_8*)(&Al[srow][koff]) = t;
    } else {
      float4 av = {0.f, 0.f, 0.f, 0.f};
      if (arow < M) av = *(const float4*)((const __bf16*)A + (size_t)arow * K + kt + koff);
      *(float4*)(&Al[srow][koff]) = av;
    }
    float4 bv = *(const float4*)(Bt + (size_t)(col0 + srow) * K + kt + koff);
    *(float4*)(&Bl[srow][koff]) = bv;
    __syncthreads();
    bf16_8 bfrag = *(const bf16_8*)(&Bl[w * 16 + r][quad * 8]);
#pragma unroll
    for (int mt = 0; mt < 4; mt++) {
      bf16_8 afrag = *(const bf16_8*)(&Al[mt * 16 + r][quad * 8]);
      acc[mt] = __builtin_amdgcn_mfma_f32_16x16x32_bf16(afrag, bfrag, acc[mt], 0, 0, 0);
    }
    __syncthreads();
  }
  int ccg = col0 + w * 16 + r;  // global output column
  __bf16* Cp; int ldc; int ccol; int P;
  if (col0 < n1) { Cp = C1; ldc = ldc1; ccol = ccg; P = P1; }
  else           { Cp = C2; ldc = ldc2; ccol = ccg - n1; P = P2; }
  int cc = (P > 1) ? ((ccol & 63) * P + (ccol >> 6)) : ccol;
  float bv = HAS_BIAS ? (float)bias[ccg] : 0.0f;
#pragma unroll
  for (int mt = 0; mt < 4; mt++) {
#pragma unroll
    for (int rr = 0; rr < 4; rr++) {
      int crow = row0 + mt * 16 + quad * 4 + rr;
      if (crow < M) Cp[(size_t)crow * ldc + cc] = (__bf16)(acc[mt][rr] + bv);
    }
  }
}

// ---------- attention logits: wave per node, head-interleaved layout ----------
__global__ void k_alar_w(const __bf16* __restrict__ xwp, const __bf16* __restrict__ as_,
                         const __bf16* __restrict__ ad_,
                         float* __restrict__ al, float* __restrict__ ar) {
  int i = blockIdx.x * 4 + (threadIdx.x >> 6);
  int lane = threadIdx.x & 63;
  if (i >= NN) return;
  u96 u = *(const u96*)(xwp + (size_t)i * GATD + lane * 6);
  float v[NH] = {bflo(u.x), bfhi(u.x), bflo(u.y), bfhi(u.y), bflo(u.z), bfhi(u.z)};
#pragma unroll
  for (int h = 0; h < NH; h++) {
    float s1 = v[h] * (float)as_[h * OUTD + lane];
    float s2 = v[h] * (float)ad_[h * OUTD + lane];
    for (int off = 32; off; off >>= 1) { s1 += __shfl_xor(s1, off); s2 += __shfl_xor(s2, off); }
    if (lane == 0) { al[i * NH + h] = s1; ar[i * NH + h] = s2; }
  }
}

// ---------- GAT: wave per node; 8-edge-unrolled dwordx3 row gather ----------
__global__ __launch_bounds__(256) void k_gat2(const __bf16* __restrict__ xwp,
    const float* __restrict__ al, const float* __restrict__ ar,
    const int* __restrict__ rowstart, const int* __restrict__ csr_src,
    const __bf16* __restrict__ bgat,
    __bf16* __restrict__ h1b, float* __restrict__ out) {
  int wv = threadIdx.x >> 6, lane = threadIdx.x & 63;
  int i = blockIdx.x * 4 + wv;           // NN % 4 == 0
  __shared__ int   src_sh[4][64];
  __shared__ __attribute__((aligned(16))) float ex_sh[4][64][NH];
  __shared__ int   mc_sh[4];
  int e0 = rowstart[i], e1 = rowstart[i + 1];
  if (lane == 0) mc_sh[wv] = (e1 - e0 + 63) >> 6;
  float arv[NH], exs[NH], acc[NH], denp[NH];
#pragma unroll
  for (int h = 0; h < NH; h++) arv[h] = ar[i * NH + h];
  u96 us = *(const u96*)(xwp + (size_t)i * GATD + lane * 6);
  float sv[NH] = {bflo(us.x), bfhi(us.x), bflo(us.y), bfhi(us.y), bflo(us.z), bfhi(us.z)};
#pragma unroll
  for (int h = 0; h < NH; h++) {
    float e = lrelu(al[i * NH + h] + arv[h], 0.2f);
    exs[h] = __expf(e);                  // self-loop weight
    acc[h] = exs[h] * sv[h];
    denp[h] = 0.f;
  }
  __syncthreads();
  int mch = max(max(mc_sh[0], mc_sh[1]), max(mc_sh[2], mc_sh[3]));
  for (int c = 0; c < mch; c++) {
    if (c) __syncthreads();
    int base = e0 + c * 64;
    int cnt = e1 - base; cnt = cnt < 0 ? 0 : (cnt > 64 ? 64 : cnt);
    // padded write: lanes >= cnt store (src=i, ex=0) so the unrolled loop has no tail
    int s = i;
    float exh[NH];
#pragma unroll
    for (int h = 0; h < NH; h++) exh[h] = 0.f;
    if (lane < cnt) {
      s = csr_src[base + lane];
#pragma unroll
      for (int h = 0; h < NH; h++)
        exh[h] = __expf(lrelu(al[s * NH + h] + arv[h], 0.2f));
    }
    src_sh[wv][lane] = s;
#pragma unroll
    for (int h = 0; h < NH; h++) { ex_sh[wv][lane][h] = exh[h]; denp[h] += exh[h]; }
    __syncthreads();
    int cntp = (cnt + 7) & ~7;
    for (int j = 0; j < cntp; j += 8) {
      int4 sa = *(const int4*)&src_sh[wv][j];
      int4 sb = *(const int4*)&src_sh[wv][j + 4];
      int sq[8] = {sa.x, sa.y, sa.z, sa.w, sb.x, sb.y, sb.z, sb.w};
      u96 u[8];
#pragma unroll
      for (int q = 0; q < 8; q++)
        u[q] = *(const u96*)(xwp + (size_t)sq[q] * GATD + lane * 6);
#pragma unroll
      for (int q = 0; q < 8; q++) {
        const float2* ep = (const float2*)ex_sh[wv][j + q];
        float2 ea = ep[0], eb = ep[1], ec = ep[2];
        acc[0] += ea.x * bflo(u[q].x);
        acc[1] += ea.y * bfhi(u[q].x);
        acc[2] += eb.x * bflo(u[q].y);
        acc[3] += eb.y * bfhi(u[q].y);
        acc[4] += ec.x * bflo(u[q].z);
        acc[5] += ec.y * bfhi(u[q].z);
      }
    }
  }
#pragma unroll
  for (int h = 0; h < NH; h++) {
    float d = denp[h];
    for (int off = 32; off; off >>= 1) d += __shfl_xor(d, off);
    d += exs[h];
    float v = acc[h] / d + (float)bgat[h * OUTD + lane];
    v = lrelu(v, 0.01f);
    h1b[(size_t)i * GATD + h * OUTD + lane] = (__bf16)v;   // standard layout (GEMM-3 A)
    out[(size_t)i * ODIM + h * OUTD + lane] = tanhf(v);
  }
}

// ---------- fused GCN0+GCN1+ARMA: wave per node; 8-edge-unrolled gather ----------
__global__ __launch_bounds__(256) void k_gcnarma2(const __bf16* __restrict__ xwgp,
    const __bf16* __restrict__ trb, const int* __restrict__ rowstart,
    const int* __restrict__ csr_src, const float* __restrict__ csr_w,
    const float* __restrict__ dgcn, const float* __restrict__ darma,
    const __bf16* __restrict__ b0, const __bf16* __restrict__ b1,
    const __bf16* __restrict__ ba, float* __restrict__ out) {
  int wv = threadIdx.x >> 6, lane = threadIdx.x & 63;
  int i = blockIdx.x * 4 + wv;
  __shared__ int   src_sh[4][64];
  __shared__ __attribute__((aligned(16))) float wg_sh[4][64], wa_sh[4][64];
  __shared__ int   mc_sh[4];
  int e0 = rowstart[i], e1 = rowstart[i + 1];
  if (lane == 0) mc_sh[wv] = (e1 - e0 + 63) >> 6;
  __syncthreads();
  int mch = max(max(mc_sh[0], mc_sh[1]), max(mc_sh[2], mc_sh[3]));
  float g0 = 0.f, g1 = 0.f, aa = 0.f;
  for (int c = 0; c < mch; c++) {
    if (c) __syncthreads();
    int base = e0 + c * 64;
    int cnt = e1 - base; cnt = cnt < 0 ? 0 : (cnt > 64 ? 64 : cnt);
    int s = i; float wgv = 0.f, wav = 0.f;
    if (lane < cnt) {
      int eidx = base + lane;
      s = csr_src[eidx];
      float wvv = csr_w[eidx];
      wgv = dgcn[s] * wvv;
      wav = darma[s] * wvv;
    }
    src_sh[wv][lane] = s;
    wg_sh[wv][lane] = wgv;
    wa_sh[wv][lane] = wav;
    __syncthreads();
    int cntp = (cnt + 7) & ~7;
    for (int j = 0; j < cntp; j += 8) {
      int4 sa = *(const int4*)&src_sh[wv][j];
      int4 sb = *(const int4*)&src_sh[wv][j + 4];
      int sq[8] = {sa.x, sa.y, sa.z, sa.w, sb.x, sb.y, sb.z, sb.w};
      unsigned x[8]; unsigned short t[8];
#pragma unroll
      for (int q = 0; q < 8; q++) {
        x[q] = *(const unsigned*)(xwgp + (size_t)sq[q] * 128 + lane * 2);
        t[q] = *(const unsigned short*)((const unsigned short*)trb + (size_t)sq[q] * 128 + lane);
      }
      float4 wg0 = *(const float4*)&wg_sh[wv][j];
      float4 wg1 = *(const float4*)&wg_sh[wv][j + 4];
      float4 wa0 = *(const float4*)&wa_sh[wv][j];
      float4 wa1 = *(const float4*)&wa_sh[wv][j + 4];
      float wgq[8] = {wg0.x, wg0.y, wg0.z, wg0.w, wg1.x, wg1.y, wg1.z, wg1.w};
      float waq[8] = {wa0.x, wa0.y, wa0.z, wa0.w, wa1.x, wa1.y, wa1.z, wa1.w};
#pragma unroll
      for (int q = 0; q < 8; q++) {
        g0 += wgq[q] * bflo(x[q]);
        g1 += wgq[q] * bfhi(x[q]);
        aa += waq[q] * bflo((unsigned)t[q]);
      }
    }
  }
  float di = dgcn[i];
  unsigned xs = *(const unsigned*)(xwgp + (size_t)i * 128 + lane * 2);
  float v0 = lrelu(di * g0 + di * di * bflo(xs) + (float)b0[lane], 0.01f);
  float v1 = lrelu(di * g1 + di * di * bfhi(xs) + (float)b1[lane], 0.01f);
  out[(size_t)i * ODIM + 384 + lane] = tanhf(v0);
  out[(size_t)i * ODIM + 448 + lane] = tanhf(v1);
  float va = darma[i] * aa + (float)trb[(size_t)i * 128 + 64 + lane] + (float)ba[lane];
  va = fmaxf(va, 0.f);
  out[(size_t)i * ODIM + 512 + lane] = tanhf(va);
}

extern "C" void kernel_launch(void* const* d_in, const int* in_sizes, int n_in,
                              void* d_out, int out_size, void* d_ws, size_t ws_size,
                              hipStream_t stream) {
  const int* ei = (const int*)d_in[1];
  float* out = (float*)d_out;

  char* ws = (char*)d_ws;
  size_t off = 0;
  auto alloc = [&](size_t bytes) -> void* {
    void* p = ws + off;
    off += (bytes + 255) & ~(size_t)255;
    return p;
  };
  int*    flags    = (int*)alloc(32 * 4);
  int*    deg      = (int*)alloc((size_t)3 * NN * 4);
  int*    cursor   = deg + NN;
  float*  wdeg     = (float*)(deg + 2 * NN);
  int*    rowstart = (int*)alloc((size_t)(NN + 1) * 4);
  int*    csr_src  = (int*)alloc((size_t)EE * 4);
  float*  csr_w    = (float*)alloc((size_t)EE * 4);
  float*  dgcn     = (float*)alloc((size_t)NN * 4);
  float*  darma    = (float*)alloc((size_t)NN * 4);
  float*  al       = (float*)alloc((size_t)NN * NH * 4);
  float*  ar       = (float*)alloc((size_t)NN * NH * 4);
  __bf16* bpb   = (__bf16*)alloc(256 * 2);
  __bf16* asb   = (__bf16*)alloc(384 * 2);
  __bf16* adb   = (__bf16*)alloc(384 * 2);
  __bf16* bgatb = (__bf16*)alloc(384 * 2);
  __bf16* bg0b  = (__bf16*)alloc(64 * 2);
  __bf16* bg1b  = (__bf16*)alloc(64 * 2);
  __bf16* bab   = (__bf16*)alloc(64 * 2);
  __bf16* Wp_t    = (__bf16*)alloc(256 * 256 * 2);
  // Wgat_t and Wg01_t in one contiguous buffer -> single fused GEMM (N=512)
  __bf16* Wcat_t  = (__bf16*)alloc((size_t)(384 + 128) * 256 * 2);
  __bf16* Wgat_t  = Wcat_t;
  __bf16* Wg01_t  = Wcat_t + (size_t)384 * 256;
  __bf16* Warma_t = (__bf16*)alloc(128 * 384 * 2);
  char* regA = (char*)alloc((size_t)NN * GATD * 2);
  __bf16* h   = (__bf16*)regA;   // dead after fused gemm
  __bf16* h1b = (__bf16*)regA;
  char* regB = (char*)alloc((size_t)NN * GATD * 2);
  __bf16* xwp = (__bf16*)regB;   // head-interleaved [n][f][h]; dead after k_gat2
  __bf16* trb = (__bf16*)regB;
  __bf16* xwgp = (__bf16*)alloc((size_t)NN * 128 * 2);  // [n][f][g]
  (void)ws_size; (void)in_sizes; (void)n_in; (void)out_size;

  hipMemsetAsync(ws, 0, 256 + (size_t)3 * NN * 4, stream);

  dim3 tb(256);
  // fused probes
  ProbeArgs pa;
  const int pidx[15] = {0, 2, 3, 4, 5, 6, 7, 8, 9, 10, 11, 12, 13, 14, 15};
  const int pcnt[15] = {NN * 256, EE, 256 * 256, 256, 256 * 384, NH * OUTD, NH * OUTD,
                        NH * OUTD, 256 * 64, 64, 256 * 64, 64, GATD * OUTD, GATD * OUTD, 64};
  for (int k = 0; k < 15; k++) { pa.ptr[k] = d_in[pidx[k]]; pa.cnt[k] = pcnt[k]; pa.flagidx[k] = pidx[k]; }
  pa.ei = ei;
  k_probe_all<<<dim3(16), tb, 0, stream>>>(pa, flags);

  // fused small-tensor conversions (biases + attention vectors)
  CvtArgs ca;
  {
    struct { int idx; __bf16* out; int n; } cv[7] = {
      {4, bpb, 256}, {6, asb, 384}, {7, adb, 384}, {8, bgatb, 384},
      {10, bg0b, 64}, {12, bg1b, 64}, {15, bab, 64},
    };
    int blk = 0;
    for (int k = 0; k < 7; k++) {
      ca.s[k].in = d_in[cv[k].idx]; ca.s[k].out = cv[k].out; ca.s[k].n = cv[k].n;
      ca.s[k].flagidx = cv[k].idx; ca.s[k].blk0 = blk;
      blk += (cv[k].n + 255) / 256;
    }
    k_cvt_all<<<dim3(blk), tb, 0, stream>>>(ca, flags);
  }

  // fused cvt+transpose for the 6 weight matrices (raw d_in -> Bt bf16)
  TArgs ta;
  {
    struct { int idx; __bf16* out; int R; int C; } tv[6] = {
      {3,  Wp_t,             256, 256},
      {5,  Wgat_t,           256, 384},
      {9,  Wg01_t,           256, 64},
      {11, Wg01_t + 64 * 256, 256, 64},
      {13, Warma_t,          384, 64},
      {14, Warma_t + 64 * 384, 384, 64},
    };
    int blk = 0;
    for (int k = 0; k < 6; k++) {
      ta.s[k].in = d_in[tv[k].idx]; ta.s[k].out = tv[k].out;
      ta.s[k].R = tv[k].R; ta.s[k].C = tv[k].C;
      ta.s[k].flagidx = tv[k].idx; ta.s[k].blk0 = blk;
      blk += ((tv[k].R + 31) / 32) * ((tv[k].C + 31) / 32);
    }
    k_cvt_t_all<<<dim3(blk), tb, 0, stream>>>(ta, flags);
  }

  // CSR by dst + degree norms
  k_count<<<dim3((EE + 255) / 256), tb, 0, stream>>>(ei, d_in[2], flags, deg, wdeg);
  k_scan<<<dim3(1), tb, 0, stream>>>(deg, rowstart);
  k_fill<<<dim3((EE + 255) / 256), tb, 0, stream>>>(ei, d_in[2], flags, rowstart, cursor, csr_src, csr_w);
  k_dinv<<<dim3((NN + 255) / 256), tb, 0, stream>>>(wdeg, dgcn, darma);

  const int MB64 = (NN + 63) / 64;  // 313
  // h = x @ Wp + bp (standard layout)
  gemm64<true ><<<dim3(MB64, 4), tb, 0, stream>>>(d_in[0], &flags[0], Wp_t, bpb,
                                                  h, 256, 256, 1, nullptr, 0, 1, NN, 256);
  // fused: xwp = perm6(h @ Wgat) (cols 0..383), xwgp = perm2(h @ Wgcn01) (cols 384..511)
  gemm64<false><<<dim3(MB64, 8), tb, 0, stream>>>(h, &flags[30], Wcat_t, nullptr,
                                                  xwp, 384, 384, 6, xwgp, 128, 2, NN, 256);
  k_alar_w<<<dim3(NN / 4), tb, 0, stream>>>(xwp, asb, adb, al, ar);
  // h dead; h1b overwrites region A
  k_gat2<<<dim3(NN / 4), tb, 0, stream>>>(xwp, al, ar, rowstart, csr_src, bgatb, h1b, out);
  // xwp dead; trb overwrites region B (identity layout)
  gemm64<false><<<dim3(MB64, 2), tb, 0, stream>>>(h1b, &flags[30], Warma_t, nullptr,
                                                  trb, 128, 128, 1, nullptr, 0, 1, NN, 384);
  k_gcnarma2<<<dim3(NN / 4), tb, 0, stream>>>(xwgp, trb, rowstart, csr_src, csr_w,
                                              dgcn, darma, bg0b, bg1b, bab, out);
}

// Round 4
// 329.496 us; speedup vs baseline: 1.0608x; 1.0599x over previous
//
#include <hip/hip_runtime.h>

// R16: consolidation. Gather kernels (k_gat2/k_gcnarma2/k_alar_w) reverted
// VERBATIM to R12's proven form (45.7us k_gat2; R14/R15 wide-load gathers
// regressed 9-25%). Kept from R13-R15: parallel k_scan, fused dual-output GEMM.
// New: GEMM block tile widened 64x64 -> 64x128 (acc[4][2], 8 MFMA/K-step):
// halves A re-reads (GEMM1 4->2, GEMM2f 8->4, GEMM4 2->1 passes over A).

#define NN 20000
#define EE 320000
#define GATD 384
#define NH 6
#define OUTD 64
#define ODIM 576

typedef __bf16 bf16_8 __attribute__((ext_vector_type(8)));
typedef float f32_4 __attribute__((ext_vector_type(4)));

__device__ __forceinline__ float lrelu(float x, float s) { return x > 0.f ? x : s * x; }

__device__ __forceinline__ float loadf(const void* p, size_t i, int f32) {
  return f32 ? ((const float*)p)[i] : (float)((const __bf16*)p)[i];
}

// ---------- fused dtype probes ----------
struct ProbeArgs {
  const void* ptr[15];
  int cnt[15];
  int flagidx[15];
  const int* ei;
};
__global__ void k_probe_all(ProbeArgs a, int* __restrict__ flags) {
  __shared__ int cnt;
  if (threadIdx.x == 0) cnt = 0;
  __syncthreads();
  int b = blockIdx.x;
  if (b < 15) {
    const unsigned short* u = (const unsigned short*)a.ptr[b];
    int m = a.cnt[b] < 2048 ? a.cnt[b] : 2048;
    int c = 0;
    for (int i = threadIdx.x; i < m; i += 256) {
      float v = __uint_as_float(((unsigned int)u[i]) << 16);
      if (!(fabsf(v) < 1e4f)) c++;
    }
    if (c) atomicAdd(&cnt, c);
    __syncthreads();
    if (threadIdx.x == 0) flags[a.flagidx[b]] = (cnt > m / 16) ? 1 : 0;
  } else {
    int c = 0;
    for (int i = threadIdx.x; i < 1024; i += 256)
      if (a.ei[2 * i + 1] != 0) c++;
    if (c) atomicAdd(&cnt, c);
    __syncthreads();
    if (threadIdx.x == 0) flags[16] = (cnt <= 2) ? 1 : 0;
  }
}

// ---------- fused small-tensor conversions (7 segments) ----------
struct CvtSeg { const void* in; __bf16* out; int n; int flagidx; int blk0; };
struct CvtArgs { CvtSeg s[7]; };
__global__ void k_cvt_all(CvtArgs a, const int* __restrict__ flags) {
  int b = blockIdx.x;
  int k = 0;
  while (k + 1 < 7 && a.s[k + 1].blk0 <= b) k++;
  const CvtSeg sg = a.s[k];
  int i = (b - sg.blk0) * 256 + threadIdx.x;
  if (i >= sg.n) return;
  sg.out[i] = flags[sg.flagidx] ? (__bf16)((const float*)sg.in)[i] : ((const __bf16*)sg.in)[i];
}

// ---------- fused cvt+transpose for weight matrices: in [R][C] (fp32|bf16) -> out [C][R] bf16 ----------
struct TSeg { const void* in; __bf16* out; int R; int C; int flagidx; int blk0; };
struct TArgs { TSeg s[6]; };
__global__ void k_cvt_t_all(TArgs a, const int* __restrict__ flags) {
  __shared__ float t[32][33];
  int b = blockIdx.x;
  int k = 0;
  while (k + 1 < 6 && a.s[k + 1].blk0 <= b) k++;
  const TSeg sg = a.s[k];
  int f32 = flags[sg.flagidx];
  int tpx = (sg.C + 31) >> 5;
  int lt = b - sg.blk0;
  int c0 = (lt % tpx) * 32, r0 = (lt / tpx) * 32;
  int tid = threadIdx.x;
  for (int idx = tid; idx < 1024; idx += 256) {
    int r = idx >> 5, c = idx & 31;
    if (r0 + r < sg.R && c0 + c < sg.C)
      t[r][c] = loadf(sg.in, (size_t)(r0 + r) * sg.C + (c0 + c), f32);
  }
  __syncthreads();
  for (int idx = tid; idx < 1024; idx += 256) {
    int r = idx >> 5, c = idx & 31;
    if (c0 + r < sg.C && r0 + c < sg.R)
      sg.out[(size_t)(c0 + r) * sg.R + (r0 + c)] = (__bf16)t[c][r];
  }
}

// ---------- CSR build ----------
__global__ void k_count(const int* __restrict__ ei, const void* __restrict__ ew,
                        const int* __restrict__ flags,
                        int* __restrict__ deg, float* __restrict__ wdeg) {
  int e = blockIdx.x * 256 + threadIdx.x;
  if (e >= EE) return;
  int sh = flags[16];
  int d = ei[(size_t)(EE + e) << sh];
  atomicAdd(&deg[d], 1);
  atomicAdd(&wdeg[d], loadf(ew, e, flags[2]));
}

// parallel scan: per-thread run sums, wave shuffle-scan, cross-wave via wsum
__global__ __launch_bounds__(256) void k_scan(const int* __restrict__ deg, int* __restrict__ rowstart) {
  __shared__ int wsum[4];
  int t = threadIdx.x;
  const int per = (NN + 255) / 256;
  int lo = t * per; if (lo > NN) lo = NN;
  int hi = lo + per; if (hi > NN) hi = NN;
  int s = 0;
  for (int i = lo; i < hi; i++) s += deg[i];
  int lane = t & 63, wv = t >> 6;
  int run = s;
  for (int off = 1; off < 64; off <<= 1) {
    int u = __shfl_up(run, off);
    if (lane >= off) run += u;
  }
  if (lane == 63) wsum[wv] = run;
  __syncthreads();
  int wbase = 0;
#pragma unroll
  for (int w = 0; w < 4; w++) { int v = wsum[w]; if (w < wv) wbase += v; }
  int a = wbase + run - s;  // exclusive prefix for this thread's run
  for (int i = lo; i < hi; i++) { rowstart[i] = a; a += deg[i]; }
  if (t == 255) rowstart[NN] = a;
}

__global__ void k_fill(const int* __restrict__ ei, const void* __restrict__ ew,
                       const int* __restrict__ flags, const int* __restrict__ rowstart,
                       int* __restrict__ cursor,
                       int* __restrict__ csr_src, float* __restrict__ csr_w) {
  int e = blockIdx.x * 256 + threadIdx.x;
  if (e >= EE) return;
  int sh = flags[16];
  int d = ei[(size_t)(EE + e) << sh];
  int s = ei[(size_t)e << sh];
  int pos = rowstart[d] + atomicAdd(&cursor[d], 1);
  csr_src[pos] = s;
  csr_w[pos] = loadf(ew, e, flags[2]);
}

__global__ void k_dinv(const float* __restrict__ wdeg, float* __restrict__ dg, float* __restrict__ da) {
  int i = blockIdx.x * 256 + threadIdx.x;
  if (i >= NN) return;
  float w = wdeg[i];
  dg[i] = rsqrtf(w + 1.0f);
  da[i] = w > 0.f ? rsqrtf(w) : 0.f;
}

// ---------- MFMA GEMM: C[M][N] = A[M][K] * Bt[N][K]^T (+bias), bf16 out ----------
// 64x128 block tile: each wave owns 2 column 16-slots (acc[4][2], 8 MFMA/K-step).
// Dual-output epilogue (col0 < n1 -> C1 else C2, col rebased); n1 % 128 == 0 so
// a whole block routes to one output.
template<bool HAS_BIAS>
__global__ __launch_bounds__(256) void gemm64(const void* __restrict__ A,
    const int* __restrict__ aflag, const __bf16* __restrict__ Bt,
    const __bf16* __restrict__ bias,
    __bf16* __restrict__ C1, int n1, int ldc1,
    __bf16* __restrict__ C2, int ldc2,
    int M, int K) {
  __shared__ __bf16 Al[64][40];
  __shared__ __bf16 Bl[128][40];
  int a32 = *aflag;
  int tid = threadIdx.x;
  int w = tid >> 6, lane = tid & 63;
  int quad = lane >> 4, r = lane & 15;
  int row0 = blockIdx.x * 64, col0 = blockIdx.y * 128;
  f32_4 acc[4][2] = {};
  int srow = tid >> 2;
  int koff = (tid & 3) * 8;
  int brow = tid >> 1;          // 0..127
  int bko  = (tid & 1) * 16;    // 0 or 16
  for (int kt = 0; kt < K; kt += 32) {
    int arow = row0 + srow;
    if (a32) {
      float4 a0 = {0.f, 0.f, 0.f, 0.f}, a1 = {0.f, 0.f, 0.f, 0.f};
      if (arow < M) {
        const float* ap = (const float*)A + (size_t)arow * K + kt + koff;
        a0 = *(const float4*)ap;
        a1 = *(const float4*)(ap + 4);
      }
      bf16_8 t;
      t[0] = (__bf16)a0.x; t[1] = (__bf16)a0.y; t[2] = (__bf16)a0.z; t[3] = (__bf16)a0.w;
      t[4] = (__bf16)a1.x; t[5] = (__bf16)a1.y; t[6] = (__bf16)a1.z; t[7] = (__bf16)a1.w;
      *(bf16_8*)(&Al[srow][koff]) = t;
    } else {
      float4 av = {0.f, 0.f, 0.f, 0.f};
      if (arow < M) av = *(const float4*)((const __bf16*)A + (size_t)arow * K + kt + koff);
      *(float4*)(&Al[srow][koff]) = av;
    }
    const __bf16* bp = Bt + (size_t)(col0 + brow) * K + kt + bko;
    *(float4*)(&Bl[brow][bko])     = *(const float4*)bp;
    *(float4*)(&Bl[brow][bko + 8]) = *(const float4*)(bp + 8);
    __syncthreads();
    bf16_8 bfrag0 = *(const bf16_8*)(&Bl[w * 16 + r][quad * 8]);
    bf16_8 bfrag1 = *(const bf16_8*)(&Bl[64 + w * 16 + r][quad * 8]);
#pragma unroll
    for (int mt = 0; mt < 4; mt++) {
      bf16_8 afrag = *(const bf16_8*)(&Al[mt * 16 + r][quad * 8]);
      acc[mt][0] = __builtin_amdgcn_mfma_f32_16x16x32_bf16(afrag, bfrag0, acc[mt][0], 0, 0, 0);
      acc[mt][1] = __builtin_amdgcn_mfma_f32_16x16x32_bf16(afrag, bfrag1, acc[mt][1], 0, 0, 0);
    }
    __syncthreads();
  }
  // whole 128-wide block routes to one output (n1 % 128 == 0)
  __bf16* Cp; int ldc; int cbase;
  if (col0 < n1) { Cp = C1; ldc = ldc1; cbase = col0; }
  else           { Cp = C2; ldc = ldc2; cbase = col0 - n1; }
  int cc0 = cbase + w * 16 + r;
  int cc1 = cbase + 64 + w * 16 + r;
  float bv0 = HAS_BIAS ? (float)bias[col0 + w * 16 + r] : 0.0f;
  float bv1 = HAS_BIAS ? (float)bias[col0 + 64 + w * 16 + r] : 0.0f;
#pragma unroll
  for (int mt = 0; mt < 4; mt++) {
#pragma unroll
    for (int rr = 0; rr < 4; rr++) {
      int crow = row0 + mt * 16 + quad * 4 + rr;
      if (crow < M) {
        Cp[(size_t)crow * ldc + cc0] = (__bf16)(acc[mt][0][rr] + bv0);
        Cp[(size_t)crow * ldc + cc1] = (__bf16)(acc[mt][1][rr] + bv1);
      }
    }
  }
}

// ---------- attention logits: wave per (node,head) ---------- (R12 verbatim)
__global__ void k_alar_w(const __bf16* __restrict__ xwb, const __bf16* __restrict__ as_,
                         const __bf16* __restrict__ ad_,
                         float* __restrict__ al, float* __restrict__ ar) {
  int p = blockIdx.x * 4 + (threadIdx.x >> 6);
  int lane = threadIdx.x & 63;
  if (p >= NN * NH) return;
  int i = p / NH, h = p - i * NH;
  float xv = (float)xwb[(size_t)i * GATD + h * OUTD + lane];
  float s1 = xv * (float)as_[h * OUTD + lane];
  float s2 = xv * (float)ad_[h * OUTD + lane];
  for (int off = 32; off; off >>= 1) { s1 += __shfl_xor(s1, off); s2 += __shfl_xor(s2, off); }
  if (lane == 0) { al[p] = s1; ar[p] = s2; }
}

// ---------- GAT: wave per node, single pass ---------- (R12 verbatim)
__global__ __launch_bounds__(256) void k_gat2(const __bf16* __restrict__ xwb,
    const float* __restrict__ al, const float* __restrict__ ar,
    const int* __restrict__ rowstart, const int* __restrict__ csr_src,
    const __bf16* __restrict__ bgat,
    __bf16* __restrict__ h1b, float* __restrict__ out) {
  int wv = threadIdx.x >> 6, lane = threadIdx.x & 63;
  int i = blockIdx.x * 4 + wv;           // NN % 4 == 0
  __shared__ int   src_sh[4][64];
  __shared__ float ex_sh[4][64][NH];
  __shared__ int   mc_sh[4];
  int e0 = rowstart[i], e1 = rowstart[i + 1];
  if (lane == 0) mc_sh[wv] = (e1 - e0 + 63) >> 6;
  float arv[NH], exs[NH], acc[NH], denp[NH];
#pragma unroll
  for (int h = 0; h < NH; h++) arv[h] = ar[i * NH + h];
#pragma unroll
  for (int h = 0; h < NH; h++) {
    float e = lrelu(al[i * NH + h] + arv[h], 0.2f);
    exs[h] = __expf(e);                  // self-loop weight
    acc[h] = exs[h] * (float)xwb[(size_t)i * GATD + h * OUTD + lane];
    denp[h] = 0.f;
  }
  __syncthreads();
  int mch = max(max(mc_sh[0], mc_sh[1]), max(mc_sh[2], mc_sh[3]));
  for (int c = 0; c < mch; c++) {
    if (c) __syncthreads();
    int base = e0 + c * 64;
    int cnt = e1 - base; cnt = cnt < 0 ? 0 : (cnt > 64 ? 64 : cnt);
    if (lane < cnt) {
      int s = csr_src[base + lane];
      src_sh[wv][lane] = s;
#pragma unroll
      for (int h = 0; h < NH; h++) {
        float ex = __expf(lrelu(al[s * NH + h] + arv[h], 0.2f));
        ex_sh[wv][lane][h] = ex;
        denp[h] += ex;
      }
    }
    __syncthreads();
    int j = 0;
    for (; j + 2 <= cnt; j += 2) {
      int s0 = src_sh[wv][j], s1 = src_sh[wv][j + 1];
      const __bf16* r0 = xwb + (size_t)s0 * GATD + lane;
      const __bf16* r1 = xwb + (size_t)s1 * GATD + lane;
      float x0[NH], x1[NH];
#pragma unroll
      for (int h = 0; h < NH; h++) { x0[h] = (float)r0[h * OUTD]; x1[h] = (float)r1[h * OUTD]; }
#pragma unroll
      for (int h = 0; h < NH; h++)
        acc[h] += ex_sh[wv][j][h] * x0[h] + ex_sh[wv][j + 1][h] * x1[h];
    }
    if (j < cnt) {
      int s0 = src_sh[wv][j];
      const __bf16* r0 = xwb + (size_t)s0 * GATD + lane;
#pragma unroll
      for (int h = 0; h < NH; h++) acc[h] += ex_sh[wv][j][h] * (float)r0[h * OUTD];
    }
  }
#pragma unroll
  for (int h = 0; h < NH; h++) {
    float d = denp[h];
    for (int off = 32; off; off >>= 1) d += __shfl_xor(d, off);
    d += exs[h];
    float v = acc[h] / d + (float)bgat[h * OUTD + lane];
    v = lrelu(v, 0.01f);
    h1b[(size_t)i * GATD + h * OUTD + lane] = (__bf16)v;
    out[(size_t)i * ODIM + h * OUTD + lane] = tanhf(v);
  }
}

// ---------- fused GCN0+GCN1+ARMA: wave per node, single pass ---------- (R12 verbatim)
__global__ __launch_bounds__(256) void k_gcnarma2(const __bf16* __restrict__ xwgb,
    const __bf16* __restrict__ trb, const int* __restrict__ rowstart,
    const int* __restrict__ csr_src, const float* __restrict__ csr_w,
    const float* __restrict__ dgcn, const float* __restrict__ darma,
    const __bf16* __restrict__ b0, const __bf16* __restrict__ b1,
    const __bf16* __restrict__ ba, float* __restrict__ out) {
  int wv = threadIdx.x >> 6, lane = threadIdx.x & 63;
  int i = blockIdx.x * 4 + wv;
  __shared__ int   src_sh[4][64];
  __shared__ float wg_sh[4][64], wa_sh[4][64];
  __shared__ int   mc_sh[4];
  int e0 = rowstart[i], e1 = rowstart[i + 1];
  if (lane == 0) mc_sh[wv] = (e1 - e0 + 63) >> 6;
  __syncthreads();
  int mch = max(max(mc_sh[0], mc_sh[1]), max(mc_sh[2], mc_sh[3]));
  float g0 = 0.f, g1 = 0.f, aa = 0.f;
  for (int c = 0; c < mch; c++) {
    if (c) __syncthreads();
    int base = e0 + c * 64;
    int cnt = e1 - base; cnt = cnt < 0 ? 0 : (cnt > 64 ? 64 : cnt);
    if (lane < cnt) {
      int eidx = base + lane;
      int s = csr_src[eidx];
      float wvv = csr_w[eidx];
      src_sh[wv][lane] = s;
      wg_sh[wv][lane] = dgcn[s] * wvv;
      wa_sh[wv][lane] = darma[s] * wvv;
    }
    __syncthreads();
    int j = 0;
    for (; j + 2 <= cnt; j += 2) {
      int s0 = src_sh[wv][j], s1 = src_sh[wv][j + 1];
      float wg0 = wg_sh[wv][j], wg1 = wg_sh[wv][j + 1];
      float wa0 = wa_sh[wv][j], wa1 = wa_sh[wv][j + 1];
      const __bf16* p0 = xwgb + (size_t)s0 * 128;
      const __bf16* p1 = xwgb + (size_t)s1 * 128;
      const __bf16* q0 = trb + (size_t)s0 * 128;
      const __bf16* q1 = trb + (size_t)s1 * 128;
      g0 += wg0 * (float)p0[lane] + wg1 * (float)p1[lane];
      g1 += wg0 * (float)p0[lane + 64] + wg1 * (float)p1[lane + 64];
      aa += wa0 * (float)q0[lane] + wa1 * (float)q1[lane];
    }
    if (j < cnt) {
      int s0 = src_sh[wv][j];
      float wg0 = wg_sh[wv][j], wa0 = wa_sh[wv][j];
      const __bf16* p0 = xwgb + (size_t)s0 * 128;
      const __bf16* q0 = trb + (size_t)s0 * 128;
      g0 += wg0 * (float)p0[lane];
      g1 += wg0 * (float)p0[lane + 64];
      aa += wa0 * (float)q0[lane];
    }
  }
  float di = dgcn[i];
  float v0 = lrelu(di * g0 + di * di * (float)xwgb[(size_t)i * 128 + lane] + (float)b0[lane], 0.01f);
  float v1 = lrelu(di * g1 + di * di * (float)xwgb[(size_t)i * 128 + 64 + lane] + (float)b1[lane], 0.01f);
  out[(size_t)i * ODIM + 384 + lane] = tanhf(v0);
  out[(size_t)i * ODIM + 448 + lane] = tanhf(v1);
  float va = darma[i] * aa + (float)trb[(size_t)i * 128 + 64 + lane] + (float)ba[lane];
  va = fmaxf(va, 0.f);
  out[(size_t)i * ODIM + 512 + lane] = tanhf(va);
}

extern "C" void kernel_launch(void* const* d_in, const int* in_sizes, int n_in,
                              void* d_out, int out_size, void* d_ws, size_t ws_size,
                              hipStream_t stream) {
  const int* ei = (const int*)d_in[1];
  float* out = (float*)d_out;

  char* ws = (char*)d_ws;
  size_t off = 0;
  auto alloc = [&](size_t bytes) -> void* {
    void* p = ws + off;
    off += (bytes + 255) & ~(size_t)255;
    return p;
  };
  int*    flags    = (int*)alloc(32 * 4);
  int*    deg      = (int*)alloc((size_t)3 * NN * 4);
  int*    cursor   = deg + NN;
  float*  wdeg     = (float*)(deg + 2 * NN);
  int*    rowstart = (int*)alloc((size_t)(NN + 1) * 4);
  int*    csr_src  = (int*)alloc((size_t)EE * 4);
  float*  csr_w    = (float*)alloc((size_t)EE * 4);
  float*  dgcn     = (float*)alloc((size_t)NN * 4);
  float*  darma    = (float*)alloc((size_t)NN * 4);
  float*  al       = (float*)alloc((size_t)NN * NH * 4);
  float*  ar       = (float*)alloc((size_t)NN * NH * 4);
  __bf16* bpb   = (__bf16*)alloc(256 * 2);
  __bf16* asb   = (__bf16*)alloc(384 * 2);
  __bf16* adb   = (__bf16*)alloc(384 * 2);
  __bf16* bgatb = (__bf16*)alloc(384 * 2);
  __bf16* bg0b  = (__bf16*)alloc(64 * 2);
  __bf16* bg1b  = (__bf16*)alloc(64 * 2);
  __bf16* bab   = (__bf16*)alloc(64 * 2);
  __bf16* Wp_t    = (__bf16*)alloc(256 * 256 * 2);
  // Wgat_t and Wg01_t contiguous -> single fused GEMM (N=512)
  __bf16* Wcat_t  = (__bf16*)alloc((size_t)(384 + 128) * 256 * 2);
  __bf16* Wgat_t  = Wcat_t;
  __bf16* Wg01_t  = Wcat_t + (size_t)384 * 256;
  __bf16* Warma_t = (__bf16*)alloc(128 * 384 * 2);
  char* regA = (char*)alloc((size_t)NN * GATD * 2);
  __bf16* h   = (__bf16*)regA;   // dead after fused gemm
  __bf16* h1b = (__bf16*)regA;
  char* regB = (char*)alloc((size_t)NN * GATD * 2);
  __bf16* xwb = (__bf16*)regB;   // dead after k_gat2
  __bf16* trb = (__bf16*)regB;
  __bf16* xwgb = (__bf16*)alloc((size_t)NN * 128 * 2);
  (void)ws_size; (void)in_sizes; (void)n_in; (void)out_size;

  hipMemsetAsync(ws, 0, 256 + (size_t)3 * NN * 4, stream);

  dim3 tb(256);
  // fused probes
  ProbeArgs pa;
  const int pidx[15] = {0, 2, 3, 4, 5, 6, 7, 8, 9, 10, 11, 12, 13, 14, 15};
  const int pcnt[15] = {NN * 256, EE, 256 * 256, 256, 256 * 384, NH * OUTD, NH * OUTD,
                        NH * OUTD, 256 * 64, 64, 256 * 64, 64, GATD * OUTD, GATD * OUTD, 64};
  for (int k = 0; k < 15; k++) { pa.ptr[k] = d_in[pidx[k]]; pa.cnt[k] = pcnt[k]; pa.flagidx[k] = pidx[k]; }
  pa.ei = ei;
  k_probe_all<<<dim3(16), tb, 0, stream>>>(pa, flags);

  // fused small-tensor conversions (biases + attention vectors)
  CvtArgs ca;
  {
    struct { int idx; __bf16* out; int n; } cv[7] = {
      {4, bpb, 256}, {6, asb, 384}, {7, adb, 384}, {8, bgatb, 384},
      {10, bg0b, 64}, {12, bg1b, 64}, {15, bab, 64},
    };
    int blk = 0;
    for (int k = 0; k < 7; k++) {
      ca.s[k].in = d_in[cv[k].idx]; ca.s[k].out = cv[k].out; ca.s[k].n = cv[k].n;
      ca.s[k].flagidx = cv[k].idx; ca.s[k].blk0 = blk;
      blk += (cv[k].n + 255) / 256;
    }
    k_cvt_all<<<dim3(blk), tb, 0, stream>>>(ca, flags);
  }

  // fused cvt+transpose for the 6 weight matrices (raw d_in -> Bt bf16)
  TArgs ta;
  {
    struct { int idx; __bf16* out; int R; int C; } tv[6] = {
      {3,  Wp_t,             256, 256},
      {5,  Wgat_t,           256, 384},
      {9,  Wg01_t,           256, 64},
      {11, Wg01_t + 64 * 256, 256, 64},
      {13, Warma_t,          384, 64},
      {14, Warma_t + 64 * 384, 384, 64},
    };
    int blk = 0;
    for (int k = 0; k < 6; k++) {
      ta.s[k].in = d_in[tv[k].idx]; ta.s[k].out = tv[k].out;
      ta.s[k].R = tv[k].R; ta.s[k].C = tv[k].C;
      ta.s[k].flagidx = tv[k].idx; ta.s[k].blk0 = blk;
      blk += ((tv[k].R + 31) / 32) * ((tv[k].C + 31) / 32);
    }
    k_cvt_t_all<<<dim3(blk), tb, 0, stream>>>(ta, flags);
  }

  // CSR by dst + degree norms
  k_count<<<dim3((EE + 255) / 256), tb, 0, stream>>>(ei, d_in[2], flags, deg, wdeg);
  k_scan<<<dim3(1), tb, 0, stream>>>(deg, rowstart);
  k_fill<<<dim3((EE + 255) / 256), tb, 0, stream>>>(ei, d_in[2], flags, rowstart, cursor, csr_src, csr_w);
  k_dinv<<<dim3((NN + 255) / 256), tb, 0, stream>>>(wdeg, dgcn, darma);

  const int MB64 = (NN + 63) / 64;  // 313
  // h = x @ Wp + bp   (N=256 -> 2 col-128 blocks)
  gemm64<true ><<<dim3(MB64, 2), tb, 0, stream>>>(d_in[0], &flags[0], Wp_t, bpb,
                                                  h, 256, 256, nullptr, 0, NN, 256);
  // fused: xwb = h @ Wgat (cols 0..383), xwgb = h @ Wgcn01 (cols 384..511); N=512 -> 4 blocks
  gemm64<false><<<dim3(MB64, 4), tb, 0, stream>>>(h, &flags[30], Wcat_t, nullptr,
                                                  xwb, 384, 384, xwgb, 128, NN, 256);
  k_alar_w<<<dim3((NN * NH + 3) / 4), tb, 0, stream>>>(xwb, asb, adb, al, ar);
  // h dead; h1b overwrites region A
  k_gat2<<<dim3(NN / 4), tb, 0, stream>>>(xwb, al, ar, rowstart, csr_src, bgatb, h1b, out);
  // xwb dead; trb overwrites region B   (N=128 -> 1 block)
  gemm64<false><<<dim3(MB64, 1), tb, 0, stream>>>(h1b, &flags[30], Warma_t, nullptr,
                                                  trb, 128, 128, nullptr, 0, NN, 384);
  k_gcnarma2<<<dim3(NN / 4), tb, 0, stream>>>(xwgb, trb, rowstart, csr_src, csr_w,
                                              dgcn, darma, bg0b, bg1b, bab, out);
}